// Round 4
// baseline (6571.547 us; speedup 1.0000x reference)
//
#include <hip/hip_runtime.h>

// DIAGNOSTIC BISECT ROUND: identical tiling/staging/epilogue to the failing
// MFMA kernel (rounds 2/3), but pure-f32 LDS + register-blocked f32 FMA dot
// instead of MFMA. If this passes -> bug is in the MFMA/fragment path.
// If this fails -> bug is in staging/tiling/epilogue indexing.
//
//   out[n,oc,oh,ow] = sum_c w[c,oc] * y[n,c,2oh,2ow]
//   y = separable FIR {1,3,3,1}/8 (vert) x {1,3,3,1}/8 (horiz), pad=1
// Per block: 256 oc x (4 oh x 16 ow). K-chunks of 32 channels.

typedef __attribute__((ext_vector_type(4))) float f32x4;

#define WPITCH 36   // floats per w row (32 k + 4 pad), 144 B (16B multiple)
#define YPITCH 36   // floats per y row
#define VPITCH 36   // floats per v row (34 cols + pad)

__global__ __launch_bounds__(256, 2)
void fused_downconv_f32diag(const float* __restrict__ x, const float* __restrict__ w,
                            float* __restrict__ out) {
    __shared__ __align__(16) float w_f[256 * WPITCH];   // 36864 B
    __shared__ __align__(16) float y_f[64 * YPITCH];    //  9216 B
    __shared__ __align__(16) float v_s[128 * VPITCH];   // 18432 B  (total 64.5 KB)

    const int tid  = threadIdx.x;
    const int lane = tid & 63;
    const int wv   = tid >> 6;          // wave id 0..3 -> oc strip of 64

    const int ow0 = blockIdx.x * 16;
    const int oh0 = blockIdx.y * 4;
    const int n   = blockIdx.z;

    const int col_lo = lane & 15;       // s offset within 16-wide tile
    const int rgrp   = lane >> 4;       // 0..3 -> oc sub-row group of 4

    float acc[4][4][4];                 // [m][nt][r]
    #pragma unroll
    for (int m = 0; m < 4; m++)
        #pragma unroll
        for (int nt = 0; nt < 4; nt++)
            #pragma unroll
            for (int r = 0; r < 4; r++) acc[m][nt][r] = 0.f;

    const int cbase = 2 * ow0 - 1;

    for (int c0 = 0; c0 < 128; c0 += 32) {
        // ---- stage w chunk: w_f[oc][k] = w[(c0+k)*256 + oc], oc = tid ----
        {
            const float* wp = w + (size_t)c0 * 256 + tid;
            #pragma unroll 4
            for (int k = 0; k < 32; k++)
                w_f[tid * WPITCH + k] = wp[k * 256];
        }
        // ---- stage v: vertical FIR, v_s[cc*4+oh_l][col], col in 0..33 ----
        {
            const float* xn = x + ((size_t)(n * 128 + c0)) * 262144;
            for (int i = tid; i < 32 * 4 * 34; i += 256) {
                int col  = i % 34;
                int t    = i / 34;
                int oh_l = t & 3;
                int cc   = t >> 2;
                int c    = cbase + col;
                float v  = 0.f;
                if ((unsigned)c < 512u) {
                    const float* xp = xn + (size_t)cc * 262144 + c;
                    int rb = 2 * (oh0 + oh_l) - 1;
                    float s0 = ((unsigned)(rb + 0) < 512u) ? xp[(size_t)(unsigned)(rb + 0) * 512] : 0.f;
                    float s1 = ((unsigned)(rb + 1) < 512u) ? xp[(size_t)(unsigned)(rb + 1) * 512] : 0.f;
                    float s2 = ((unsigned)(rb + 2) < 512u) ? xp[(size_t)(unsigned)(rb + 2) * 512] : 0.f;
                    float s3 = ((unsigned)(rb + 3) < 512u) ? xp[(size_t)(unsigned)(rb + 3) * 512] : 0.f;
                    v = 0.125f * (s0 + s3) + 0.375f * (s1 + s2);
                }
                v_s[(cc * 4 + oh_l) * VPITCH + col] = v;
            }
        }
        __syncthreads();

        // ---- y phase: horizontal FIR -> y_f[s][cc] (s = oh_l*16 + ow_l) ----
        for (int i = tid; i < 32 * 64; i += 256) {
            int s    = i & 63;
            int cc   = i >> 6;
            int oh_l = s >> 4;
            int ow_l = s & 15;
            const float* vp = &v_s[(cc * 4 + oh_l) * VPITCH + 2 * ow_l];
            y_f[s * YPITCH + cc] = 0.125f * (vp[0] + vp[3]) + 0.375f * (vp[1] + vp[2]);
        }
        __syncthreads();

        // ---- f32 dot: thread covers oc = wv*64 + m*16 + rgrp*4 + r, s = nt*16 + col_lo ----
        #pragma unroll
        for (int k4 = 0; k4 < 8; k4++) {
            f32x4 yv[4];
            #pragma unroll
            for (int nt = 0; nt < 4; nt++)
                yv[nt] = *(const f32x4*)&y_f[(nt * 16 + col_lo) * YPITCH + k4 * 4];
            #pragma unroll
            for (int m = 0; m < 4; m++) {
                #pragma unroll
                for (int r = 0; r < 4; r++) {
                    f32x4 wv4 = *(const f32x4*)&w_f[(wv * 64 + m * 16 + rgrp * 4 + r) * WPITCH + k4 * 4];
                    #pragma unroll
                    for (int nt = 0; nt < 4; nt++)
                        acc[m][nt][r] += wv4[0] * yv[nt][0] + wv4[1] * yv[nt][1]
                                       + wv4[2] * yv[nt][2] + wv4[3] * yv[nt][3];
                }
            }
        }
        __syncthreads();   // before next chunk overwrites LDS
    }

    // ---- epilogue: identical mapping to MFMA version's m89 layout ----
    #pragma unroll
    for (int m = 0; m < 4; m++) {
        int oc = wv * 64 + m * 16 + rgrp * 4;
        #pragma unroll
        for (int nt = 0; nt < 4; nt++) {
            size_t base = (((size_t)n * 256 + oc) * 256 + (size_t)(oh0 + nt)) * 256
                          + ow0 + col_lo;
            #pragma unroll
            for (int r = 0; r < 4; r++)
                out[base + (size_t)r * 65536] = acc[m][nt][r];
        }
    }
}

extern "C" void kernel_launch(void* const* d_in, const int* in_sizes, int n_in,
                              void* d_out, int out_size, void* d_ws, size_t ws_size,
                              hipStream_t stream) {
    const float* x = (const float*)d_in[0];
    const float* w = (const float*)d_in[1];
    float* out = (float*)d_out;

    dim3 grid(16, 64, 4);   // ow-tiles, oh-tiles, n
    dim3 block(256);
    hipLaunchKernelGGL(fused_downconv_f32diag, grid, block, 0, stream, x, w, out);
}

// Round 6
// 1353.204 us; speedup vs baseline: 4.8563x; 4.8563x over previous
//
#include <hip/hip_runtime.h>

// Fused StyleGAN2 conv_downsample_2d, optimized f32-VALU version.
//   out[n,oc,oh,ow] = sum_c w[c,oc] * y[n,c,2oh,2ow]
//   y = separable FIR {1,3,3,1}/8 (vert) x {1,3,3,1}/8 (horiz), pad=1
//
// NOTE: bf16-MFMA path abandoned: measured per-term ~3.6% noise (e4m3-class)
// in the mfma_f32_16x16x32_bf16 path -> absmax ~0.7 > 0.4325 threshold,
// precision-split-invariant (rounds 2/3/5). f32 VALU floor (109 us compute /
// ~192 us memory) is close to the MFMA ceiling for this op anyway.
//
// Block: 512 threads; tile = 256 oc x (8 oh x 16 ow) = 128 sp, one batch n.
// K-chunks of 16 channels: stage x patch (18x34/ch) + w slice in LDS,
// separable FIR in registers -> y_s[cc][sp], register-blocked 8oc x 8sp GEMM.

#define CH   16
#define PH   18
#define PW   34
#define PWP  36    // padded x row pitch (floats)
#define YP   136   // y_s row pitch (floats)

__global__ __launch_bounds__(512, 4)
void fused_downconv_f32opt(const float* __restrict__ x, const float* __restrict__ w,
                           float* __restrict__ out) {
    __shared__ __align__(16) float x_s[CH][PH][PWP];  // 41472 B
    __shared__ __align__(16) float w_s[CH][256];      // 16384 B
    __shared__ __align__(16) float y_s[CH][YP];       //  8704 B  (total 66560 B)

    const int tid  = threadIdx.x;
    const int oc_g = tid >> 4;    // 0..31 -> oc block of 8
    const int sp_g = tid & 15;    // 0..15 -> sp block of 8

    const int ow0 = blockIdx.x * 16;
    const int oh0 = blockIdx.y * 8;
    const int n   = blockIdx.z;

    float acc[8][8];
    #pragma unroll
    for (int i = 0; i < 8; i++)
        #pragma unroll
        for (int j = 0; j < 8; j++) acc[i][j] = 0.f;

    const int rbase = 2 * oh0 - 1;
    const int cbase = 2 * ow0 - 1;

    // y-phase thread mapping: cc = tid>>5, oh_l = (tid&31)>>2, 4 consecutive ow
    const int yp_cc  = tid >> 5;         // 0..15
    const int yp_ohl = (tid & 31) >> 2;  // 0..7
    const int yp_ow4 = (tid & 3) * 4;    // 0,4,8,12
    const int yp_cl0 = yp_ow4 * 2;       // 0,8,16,24 -> cols [cl0, cl0+10)

    for (int c0 = 0; c0 < 128; c0 += CH) {
        // ---- stage w slice: w_s[cc][oc], 4096 elems / 512 thr = 8 each ----
        #pragma unroll
        for (int k = 0; k < 8; k++) {
            int idx = tid + k * 512;
            int cc  = idx >> 8;
            int oc  = idx & 255;
            w_s[cc][oc] = w[(c0 + cc) * 256 + oc];
        }
        // ---- stage x patch: 16 ch x 18 x 34, zero-padded at borders ----
        {
            const float* xn = x + ((size_t)(n * 128 + c0)) * 262144;
            for (int i = tid; i < CH * PH * PW; i += 512) {
                int cc  = i / (PH * PW);
                int rem = i - cc * (PH * PW);
                int rr  = rem / PW;
                int c2  = rem - rr * PW;
                int r   = rbase + rr;
                int cl  = cbase + c2;
                float v = 0.f;
                if ((unsigned)r < 512u && (unsigned)cl < 512u)
                    v = xn[(size_t)cc * 262144 + (size_t)r * 512 + cl];
                x_s[cc][rr][c2] = v;
            }
        }
        __syncthreads();

        // ---- y phase: separable FIR in registers; 4 y per thread ----
        {
            const int r0 = yp_ohl * 2;
            float colv[10];
            #pragma unroll
            for (int j = 0; j < 10; j++) {
                int cl = yp_cl0 + j;
                colv[j] = 0.125f * (x_s[yp_cc][r0 + 0][cl] + x_s[yp_cc][r0 + 3][cl])
                        + 0.375f * (x_s[yp_cc][r0 + 1][cl] + x_s[yp_cc][r0 + 2][cl]);
            }
            #pragma unroll
            for (int q = 0; q < 4; q++) {
                float yv = 0.125f * (colv[2 * q] + colv[2 * q + 3])
                         + 0.375f * (colv[2 * q + 1] + colv[2 * q + 2]);
                y_s[yp_cc][yp_ohl * 16 + yp_ow4 + q] = yv;
            }
        }
        __syncthreads();

        // ---- GEMM: 8 oc x 8 sp register tile per thread ----
        #pragma unroll
        for (int cc = 0; cc < CH; cc++) {
            float4 wa = *(const float4*)&w_s[cc][oc_g * 8];
            float4 wb = *(const float4*)&w_s[cc][oc_g * 8 + 4];
            float4 ya = *(const float4*)&y_s[cc][sp_g * 8];
            float4 yb = *(const float4*)&y_s[cc][sp_g * 8 + 4];
            float wv[8] = {wa.x, wa.y, wa.z, wa.w, wb.x, wb.y, wb.z, wb.w};
            float yv[8] = {ya.x, ya.y, ya.z, ya.w, yb.x, yb.y, yb.z, yb.w};
            #pragma unroll
            for (int i = 0; i < 8; i++)
                #pragma unroll
                for (int j = 0; j < 8; j++)
                    acc[i][j] += wv[i] * yv[j];
        }
        __syncthreads();   // before next chunk overwrites LDS
    }

    // ---- epilogue: sp = sp_g*8 + j -> oh_l = sp_g>>1, ow = (sp_g&1)*8 + j ----
    {
        const int oh_l = sp_g >> 1;
        const int owst = (sp_g & 1) * 8;
        const size_t obase = (((size_t)n * 256 + (size_t)oc_g * 8) * 256
                              + (size_t)(oh0 + oh_l)) * 256 + ow0 + owst;
        #pragma unroll
        for (int i = 0; i < 8; i++) {
            float4 v0 = make_float4(acc[i][0], acc[i][1], acc[i][2], acc[i][3]);
            float4 v1 = make_float4(acc[i][4], acc[i][5], acc[i][6], acc[i][7]);
            *(float4*)&out[obase + (size_t)i * 65536]     = v0;
            *(float4*)&out[obase + (size_t)i * 65536 + 4] = v1;
        }
    }
}

extern "C" void kernel_launch(void* const* d_in, const int* in_sizes, int n_in,
                              void* d_out, int out_size, void* d_ws, size_t ws_size,
                              hipStream_t stream) {
    const float* x = (const float*)d_in[0];
    const float* w = (const float*)d_in[1];
    float* out = (float*)d_out;

    dim3 grid(16, 32, 4);   // ow-tiles(16 wide), oh-tiles(8 tall), n
    dim3 block(512);
    hipLaunchKernelGGL(fused_downconv_f32opt, grid, block, 0, stream, x, w, out);
}

// Round 7
// 580.098 us; speedup vs baseline: 11.3283x; 2.3327x over previous
//
#include <hip/hip_runtime.h>

// Fused StyleGAN2 conv_downsample_2d, f32-VALU, spill-free + bank-tuned.
//   out[n,oc,oh,ow] = sum_c w[c,oc] * y[n,c,2oh,2ow]
//   y = separable FIR {1,3,3,1}/8 (vert) x {1,3,3,1}/8 (horiz), pad=1
//
// Lessons encoded here:
//  - bf16 MFMA path gives ~3.6%-per-term noise on this op -> fails 0.4325
//    threshold (rounds 2/3/5). f32 VALU it is.
//  - __launch_bounds__ with a min-waves arg forced a 64-VGPR cap -> 64-float
//    acc spilled -> 2.5 GB scratch writes (round 6). Plain (512) lets the
//    allocator take ~100 VGPR like round 1's proven 76-VGPR no-spill config.
//  - y_s GEMM reads were 4-way bank-conflicted, y-phase x_s reads 8-way ->
//    swizzled y offsets (g*8 + 4*(g>>2)) and odd x pitches (35 / 631).
//
// Block: 512 threads; tile = 256 oc x (8 oh x 16 ow) = 128 sp, one batch n.
// K-chunks of 16 channels.

#define CH    16
#define PH    18
#define PW    34
#define PWP   35            // x_s row pitch (odd -> rows spread over banks)
#define CSTR  (PH*PWP + 1)  // 631, odd per-channel stride
#define YPIT  144           // y_s per-channel pitch (max off 132+8=140)

__device__ __forceinline__ int yoff(int g) { return g * 8 + ((g >> 2) << 2); }

__global__ __launch_bounds__(512)
void fused_downconv_f32v2(const float* __restrict__ x, const float* __restrict__ w,
                          float* __restrict__ out) {
    __shared__ __align__(16) float x_s[CH * CSTR];   // 40384 B
    __shared__ __align__(16) float w_s[CH][256];     // 16384 B
    __shared__ __align__(16) float y_s[CH * YPIT];   //  9216 B  (total 65984 B)

    const int tid  = threadIdx.x;
    const int oc_g = tid >> 4;    // 0..31 -> oc block of 8
    const int sp_g = tid & 15;    // 0..15 -> sp block of 8

    const int ow0 = blockIdx.x * 16;
    const int oh0 = blockIdx.y * 8;
    const int n   = blockIdx.z;

    float acc[8][8];
    #pragma unroll
    for (int i = 0; i < 8; i++)
        #pragma unroll
        for (int j = 0; j < 8; j++) acc[i][j] = 0.f;

    const int rbase = 2 * oh0 - 1;
    const int cbase = 2 * ow0 - 1;

    // y-phase mapping: cc = tid>>5, ohl = (tid&31)>>2, 4 consecutive ow
    const int yp_cc  = tid >> 5;         // 0..15
    const int yp_ohl = (tid & 31) >> 2;  // 0..7
    const int yp_ow4 = (tid & 3) * 4;    // 0,4,8,12
    const int yp_cl0 = yp_ow4 * 2;       // 0,8,16,24
    const int yp_g   = yp_ohl * 2 + (yp_ow4 >> 3);         // sp group
    const int yp_dst = yp_cc * YPIT + yoff(yp_g) + (yp_ow4 & 4);

    const int y_rd_a = sp_g * 0 + yoff(sp_g);  // GEMM y offsets (per thread)

    for (int c0 = 0; c0 < 128; c0 += CH) {
        // ---- stage w slice: w_s[cc][oc], 4096 elems / 512 thr = 8 each ----
        #pragma unroll
        for (int k = 0; k < 8; k++) {
            int idx = tid + k * 512;
            int cc  = idx >> 8;
            int oc  = idx & 255;
            w_s[cc][oc] = w[(c0 + cc) * 256 + oc];
        }
        // ---- stage x patch: 16 ch x 18 x 34, zero-padded at borders ----
        {
            const float* xn = x + ((size_t)(n * 128 + c0)) * 262144;
            for (int i = tid; i < CH * PH * PW; i += 512) {
                int cc  = i / (PH * PW);
                int rem = i - cc * (PH * PW);
                int rr  = rem / PW;
                int c2  = rem - rr * PW;
                int r   = rbase + rr;
                int cl  = cbase + c2;
                float v = 0.f;
                if ((unsigned)r < 512u && (unsigned)cl < 512u)
                    v = xn[(size_t)cc * 262144 + (size_t)r * 512 + cl];
                x_s[cc * CSTR + rr * PWP + c2] = v;
            }
        }
        __syncthreads();

        // ---- y phase: separable FIR in registers; 4 y per thread ----
        {
            const int r0 = yp_ohl * 2;
            const float* xb = &x_s[yp_cc * CSTR + r0 * PWP + yp_cl0];
            float colv[10];
            #pragma unroll
            for (int j = 0; j < 10; j++)
                colv[j] = 0.125f * (xb[j] + xb[3 * PWP + j])
                        + 0.375f * (xb[PWP + j] + xb[2 * PWP + j]);
            float4 yv4;
            yv4.x = 0.125f * (colv[0] + colv[3]) + 0.375f * (colv[1] + colv[2]);
            yv4.y = 0.125f * (colv[2] + colv[5]) + 0.375f * (colv[3] + colv[4]);
            yv4.z = 0.125f * (colv[4] + colv[7]) + 0.375f * (colv[5] + colv[6]);
            yv4.w = 0.125f * (colv[6] + colv[9]) + 0.375f * (colv[7] + colv[8]);
            *(float4*)&y_s[yp_dst] = yv4;
        }
        __syncthreads();

        // ---- GEMM: 8 oc x 8 sp register tile per thread ----
        #pragma unroll 4
        for (int cc = 0; cc < CH; cc++) {
            float4 wa = *(const float4*)&w_s[cc][oc_g * 8];
            float4 wb = *(const float4*)&w_s[cc][oc_g * 8 + 4];
            float4 ya = *(const float4*)&y_s[cc * YPIT + y_rd_a];
            float4 yb = *(const float4*)&y_s[cc * YPIT + y_rd_a + 4];
            float wv[8] = {wa.x, wa.y, wa.z, wa.w, wb.x, wb.y, wb.z, wb.w};
            float yv[8] = {ya.x, ya.y, ya.z, ya.w, yb.x, yb.y, yb.z, yb.w};
            #pragma unroll
            for (int i = 0; i < 8; i++)
                #pragma unroll
                for (int j = 0; j < 8; j++)
                    acc[i][j] += wv[i] * yv[j];
        }
        __syncthreads();   // before next chunk overwrites LDS
    }

    // ---- epilogue: sp = sp_g*8 + j -> oh_l = sp_g>>1, ow = (sp_g&1)*8 + j ----
    {
        const int oh_l = sp_g >> 1;
        const int owst = (sp_g & 1) * 8;
        const size_t obase = (((size_t)n * 256 + (size_t)oc_g * 8) * 256
                              + (size_t)(oh0 + oh_l)) * 256 + ow0 + owst;
        #pragma unroll
        for (int i = 0; i < 8; i++) {
            float4 v0 = make_float4(acc[i][0], acc[i][1], acc[i][2], acc[i][3]);
            float4 v1 = make_float4(acc[i][4], acc[i][5], acc[i][6], acc[i][7]);
            *(float4*)&out[obase + (size_t)i * 65536]     = v0;
            *(float4*)&out[obase + (size_t)i * 65536 + 4] = v1;
        }
    }
}

extern "C" void kernel_launch(void* const* d_in, const int* in_sizes, int n_in,
                              void* d_out, int out_size, void* d_ws, size_t ws_size,
                              hipStream_t stream) {
    const float* x = (const float*)d_in[0];
    const float* w = (const float*)d_in[1];
    float* out = (float*)d_out;

    dim3 grid(16, 32, 4);   // ow-tiles(16 wide), oh-tiles(8 tall), n
    dim3 block(512);
    hipLaunchKernelGGL(fused_downconv_f32v2, grid, block, 0, stream, x, w, out);
}